// Round 11
// baseline (334.619 us; speedup 1.0000x reference)
//
#include <hip/hip_runtime.h>
#include <stdint.h>

// Gaussian kernel matrix K[i][j] = exp(-||x_i-x_j||^2/2), X: [16384][64] fp32.
// R11: DRAM page-locality probe. All prior levers flat at ~4.8 TB/s (span>=128B,
// occupancy 2->3, outstanding depth, VALU trim). Fill hits 6.6 TB/s streaming
// >=4KB per DRAM page; our tiles deliver only 512B/page-visit (64KB row stride
// = every row its own page set). This kernel: 16-row x 512-col steps, 4 waves
// cooperating via a double-buffered LDS tile image; per step each wave sweeps
// 4 rows x 2KB SEQUENTIAL per row (2 back-to-back 1KB stores) = 4x the
// page-visit granularity. One barrier/step (dbuf overlaps sweep(t) with
// compute(t+1)). XOR bank swizzle keeps both LDS phases at the b128 floor.
// 3-slot load rotation => all vmcnt waits counted (<=8 outstanding stores),
// never a store drain. Prepass (Xb bf16 + premultiplied norms) from R10.

typedef __attribute__((ext_vector_type(8))) short  s16x8;  // 8 bf16 (MFMA A/B frag)
typedef __attribute__((ext_vector_type(4))) float  f32x4;
typedef __attribute__((ext_vector_type(4))) unsigned short u16x4;

#define DDIM 64
#define NT 16     // steps per block (block covers 16 rows x 8192 cols)
#define LOG2E      1.4426950408889634f   // 2c
#define HALF_LOG2E 0.7213475204444817f   // c ; K = exp2(-c||i||^2 - c||j||^2 + 2c dot)

// fp32 -> bf16 RNE on the bit pattern.
__device__ inline unsigned short bf16_rne(float x) {
  uint32_t u = __builtin_bit_cast(uint32_t, x);
  uint32_t r = (u + 0x7fffu + ((u >> 16) & 1u));
  return (unsigned short)(r >> 16);
}
__device__ inline float bf16_to_f32(unsigned short h) {
  return __builtin_bit_cast(float, (uint32_t)h << 16);
}

// ---- pre-pass 1: X (f32) -> Xb (bf16), flat coalesced ----
__global__ __launch_bounds__(256) void k_cvt(const float* __restrict__ X,
                                             unsigned short* __restrict__ Xb) {
  int g = blockIdx.x * 256 + threadIdx.x;
  f32x4 v = reinterpret_cast<const f32x4*>(X)[g];
  u16x4 h;
  h[0] = bf16_rne(v[0]); h[1] = bf16_rne(v[1]);
  h[2] = bf16_rne(v[2]); h[3] = bf16_rne(v[3]);
  reinterpret_cast<u16x4*>(Xb)[g] = h;
}

// ---- pre-pass 2: premultiplied row norms from the bf16 table ----
__global__ __launch_bounds__(256) void k_norm(const unsigned short* __restrict__ Xb,
                                              float* __restrict__ nrm) {
  int row = blockIdx.x * 256 + threadIdx.x;
  const s16x8* p = reinterpret_cast<const s16x8*>(Xb + (size_t)row * DDIM);
  float s = 0.f;
#pragma unroll
  for (int k = 0; k < 8; ++k) {
    s16x8 h = p[k];
#pragma unroll
    for (int e = 0; e < 8; ++e) {
      float f = bf16_to_f32((unsigned short)h[e]);
      s += f * f;
    }
  }
  nrm[row] = -HALF_LOG2E * s;
}

// ---- main: grid (n/16, n/8192). Block 256 thr / 4 waves; 16x512 per step ----
__global__ __launch_bounds__(256, 2) void gauss_sweep(
    const unsigned short* __restrict__ Xb, const float* __restrict__ nrm,
    float* __restrict__ K, int n) {
  const int lane = threadIdx.x & 63;
  const int wid  = threadIdx.x >> 6;   // wave owns cols [wid*128, +128) per step
  const int l15  = lane & 15;
  const int lq   = lane >> 4;          // 0..3

  // Double-buffered tile image: 16 rows x 512 floats each (2KB/row, bank-exact).
  __shared__ float sbuf[2][16 * 512];

  const int i0    = blockIdx.x * 16;     // block's 16 output rows
  const int jbase = blockIdx.y * 8192;   // 8192-col strip

  // ---- A fragments (MFMA-ready bf16) + this lane's row norm ----
  s16x8 a0 = *reinterpret_cast<const s16x8*>(Xb + (size_t)(i0 + l15) * DDIM + lq * 8);
  s16x8 a1 = *reinterpret_cast<const s16x8*>(Xb + (size_t)(i0 + l15) * DDIM + 32 + lq * 8);
  const float hA = nrm[i0 + l15];

  // ---- B / col-norm loads: 3-slot rotation over sub-steps u = t*2+s ----
  s16x8 b[3][4][2];
  f32x4 hc[3][4];
#define SUBCOL(u) (jbase + ((u) >> 1) * 512 + wid * 128 + ((u) & 1) * 64)
#define ISSUE(u)                                                               \
  do {                                                                         \
    const int slot_ = (u) % 3;                                                 \
    const int jc_ = SUBCOL(u);                                                 \
    _Pragma("unroll") for (int ni = 0; ni < 4; ++ni) {                         \
      const size_t row_ = (size_t)(jc_ + ni * 16 + l15);                       \
      b[slot_][ni][0] = *reinterpret_cast<const s16x8*>(                       \
          Xb + row_ * DDIM + lq * 8);                                          \
      b[slot_][ni][1] = *reinterpret_cast<const s16x8*>(                       \
          Xb + row_ * DDIM + 32 + lq * 8);                                     \
      hc[slot_][ni] = *reinterpret_cast<const f32x4*>(                         \
          nrm + jc_ + ni * 16 + lq * 4);                                       \
    }                                                                          \
  } while (0)

  ISSUE(0);
  ISSUE(1);

#pragma unroll
  for (int t = 0; t < NT; ++t) {
    const int p = t & 1;

#pragma unroll
    for (int s = 0; s < 2; ++s) {
      const int u = t * 2 + s;
      const int slot = u % 3;
      const int jc = SUBCOL(u);

      // prefetch sub-step u+2 (always issued BEFORE the sweep stores of this
      // step, so vmcnt waits for it never drain the store queue)
      if (u + 2 < 2 * NT) ISSUE(u + 2);
      // Pin VMEM order only; VALU/SALU/MFMA may cross for interleave.
      __builtin_amdgcn_sched_barrier(0x1 | 0x2 | 0x4 | 0x8);

      // MFMA, swapped operands: lane = output row i0+l15; acc[ni][r] =
      // dot(row i0+l15, col jc+ni*16+lq*4+r)
      f32x4 acc[4] = {};
#pragma unroll
      for (int ni = 0; ni < 4; ++ni)
        acc[ni] = __builtin_amdgcn_mfma_f32_16x16x32_bf16(
            b[slot][ni][0], a0, acc[ni], 0, 0, 0);
#pragma unroll
      for (int ni = 0; ni < 4; ++ni)
        acc[ni] = __builtin_amdgcn_mfma_f32_16x16x32_bf16(
            b[slot][ni][1], a1, acc[ni], 0, 0, 0);

      const bool diag = (i0 < jc + 64) && (jc < i0 + 16);   // uniform branch

      // exp -> LDS image (XOR swizzle: chunk ^ (row&7), rows bank-aligned)
#pragma unroll
      for (int ni = 0; ni < 4; ++ni) {
        const int c0 = jc + ni * 16 + lq * 4;
        f32x4 v;
        if (diag) {
#pragma unroll
          for (int r = 0; r < 4; ++r) {
            float e = exp2f(hA + hc[slot][ni][r] + LOG2E * acc[ni][r]);
            v[r] = (i0 + l15 == c0 + r) ? 1.0f : e;   // exact diagonal
          }
        } else {
#pragma unroll
          for (int r = 0; r < 4; ++r)
            v[r] = exp2f(hA + hc[slot][ni][r] + LOG2E * acc[ni][r]);
        }
        const int chunk = wid * 32 + s * 16 + ni * 4 + lq;   // 16B chunk in row
        const int pos = chunk ^ (l15 & 7);
        *reinterpret_cast<f32x4*>(&sbuf[p][l15 * 512 + pos * 4]) = v;
      }
    }

    // ---- one barrier: all waves' LDS writes visible (lgkm only, NOT vmcnt —
    //      sweep stores of step t-1 stay in flight) ----
    asm volatile("s_waitcnt lgkmcnt(0)" ::: "memory");
    __builtin_amdgcn_s_barrier();
    __builtin_amdgcn_sched_barrier(0);

    // ---- page sweep: wave wid stores rows [wid*4, +4), 2KB sequential/row ----
    const int jc0 = jbase + t * 512;
#pragma unroll
    for (int r = 0; r < 4; ++r) {
      const int row = wid * 4 + r;
#pragma unroll
      for (int q = 0; q < 2; ++q) {        // 2 back-to-back 1KB stores, same row
        const int g = q * 64 + lane;       // global 16B chunk in this row window
        f32x4 v = *reinterpret_cast<const f32x4*>(
            &sbuf[p][row * 512 + (g ^ (row & 7)) * 4]);
        *reinterpret_cast<f32x4*>(K + (size_t)(i0 + row) * n + jc0 + g * 4) = v;
      }
    }
  }
#undef ISSUE
#undef SUBCOL
}

// ================= R9 fallback (used only if ws_size too small) =============
__device__ inline short cvt1(float x, float& sq) {
  uint32_t u = __builtin_bit_cast(uint32_t, x);
  uint32_t r = (u + 0x7fffu + ((u >> 16) & 1u)) & 0xffff0000u;
  float hf = __builtin_bit_cast(float, r);
  sq += hf * hf;
  return (short)(r >> 16);
}
__device__ inline void issue_row(const float* __restrict__ X, int row, int lq,
                                 f32x4 r[4]) {
  const f32x4* p = reinterpret_cast<const f32x4*>(X + (size_t)row * DDIM + lq * 8);
  const f32x4* q = reinterpret_cast<const f32x4*>(X + (size_t)row * DDIM + 32 + lq * 8);
  r[0] = p[0]; r[1] = p[1]; r[2] = q[0]; r[3] = q[1];
}
__device__ inline void cvt_row(const f32x4 r[4], s16x8 h[2], float& hnorm) {
  float s = 0.f;
#pragma unroll
  for (int ks = 0; ks < 2; ++ks) {
    s16x8 hh;
    hh[0] = cvt1(r[2*ks][0], s);   hh[1] = cvt1(r[2*ks][1], s);
    hh[2] = cvt1(r[2*ks][2], s);   hh[3] = cvt1(r[2*ks][3], s);
    hh[4] = cvt1(r[2*ks+1][0], s); hh[5] = cvt1(r[2*ks+1][1], s);
    hh[6] = cvt1(r[2*ks+1][2], s); hh[7] = cvt1(r[2*ks+1][3], s);
    h[ks] = hh;
  }
  s += __shfl_xor(s, 16);
  s += __shfl_xor(s, 32);
  hnorm = -HALF_LOG2E * s;
}
__global__ __launch_bounds__(256, 2) void gauss_gram_kernel(
    const float* __restrict__ X, float* __restrict__ K, int n) {
  const int lane = threadIdx.x & 63;
  const int wid  = threadIdx.x >> 6;
  const int wr = wid >> 1, wc = wid & 1;
  const int l15 = lane & 15, lq = lane >> 4;
  const int e16 = lane & 15, r4 = lane >> 4;
  __shared__ float tbuf[4][64 * 68];
  float* buf = tbuf[wid];
  const int i0 = blockIdx.x * 128 + wr * 64;
  const int jstrip = blockIdx.y * (128 * 8);
  f32x4 araw[4][4];
#pragma unroll
  for (int mi = 0; mi < 4; ++mi) issue_row(X, i0 + mi * 16 + l15, lq, araw[mi]);
  f32x4 braw[4][4];
#pragma unroll
  for (int ni = 0; ni < 4; ++ni)
    issue_row(X, jstrip + wc * 64 + ni * 16 + l15, lq, braw[ni]);
  s16x8 a[4][2]; float hA[4];
#pragma unroll
  for (int mi = 0; mi < 4; ++mi) cvt_row(araw[mi], a[mi], hA[mi]);
#pragma unroll
  for (int jt = 0; jt < 8; ++jt) {
    const int j0 = jstrip + jt * 128 + wc * 64;
    s16x8 b[4][2]; float hcol[4][4];
#pragma unroll
    for (int ni = 0; ni < 4; ++ni) {
      float hB;
      cvt_row(braw[ni], b[ni], hB);
#pragma unroll
      for (int r = 0; r < 4; ++r) hcol[ni][r] = __shfl(hB, lq * 4 + r);
    }
    if (jt + 1 < 8) {
#pragma unroll
      for (int ni = 0; ni < 4; ++ni)
        issue_row(X, jstrip + (jt + 1) * 128 + wc * 64 + ni * 16 + l15, lq, braw[ni]);
    }
    __builtin_amdgcn_sched_barrier(0x1 | 0x2 | 0x4 | 0x8);
    f32x4 acc[4][4] = {};
#pragma unroll
    for (int ks = 0; ks < 2; ++ks)
#pragma unroll
      for (int mi = 0; mi < 4; ++mi)
#pragma unroll
        for (int ni = 0; ni < 4; ++ni)
          acc[mi][ni] = __builtin_amdgcn_mfma_f32_16x16x32_bf16(
              b[ni][ks], a[mi][ks], acc[mi][ni], 0, 0, 0);
#pragma unroll
    for (int mi = 0; mi < 4; ++mi) {
      const int rg = i0 + mi * 16 + l15;
#pragma unroll
      for (int ni = 0; ni < 4; ++ni) {
        const int c0 = j0 + ni * 16 + lq * 4;
        f32x4 v;
#pragma unroll
        for (int r = 0; r < 4; ++r) {
          float arg = fminf(hA[mi] + hcol[ni][r] + LOG2E * acc[mi][ni][r], 0.0f);
          float e = exp2f(arg);
          v[r] = (rg == c0 + r) ? 1.0f : e;
        }
        *reinterpret_cast<f32x4*>(buf + (mi * 16 + l15) * 68 + ni * 16 + lq * 4) = v;
      }
    }
#pragma unroll
    for (int g = 0; g < 16; ++g) {
      const int row = g * 4 + r4;
      f32x4 t = *reinterpret_cast<const f32x4*>(buf + row * 68 + e16 * 4);
      *reinterpret_cast<f32x4*>(K + (size_t)(i0 + row) * n + j0 + e16 * 4) = t;
    }
  }
}
// ============================================================================

extern "C" void kernel_launch(void* const* d_in, const int* in_sizes, int n_in,
                              void* d_out, int out_size, void* d_ws, size_t ws_size,
                              hipStream_t stream) {
  (void)n_in; (void)out_size;
  const float* X = (const float*)d_in[0];
  float* K = (float*)d_out;
  const int n = in_sizes[0] / DDIM;              // 16384
  const size_t need = (size_t)n * DDIM * 2 + (size_t)n * 4;  // Xb + nrm
  if (ws_size >= need) {
    unsigned short* Xb = (unsigned short*)d_ws;
    float* nrm = (float*)((char*)d_ws + (size_t)n * DDIM * 2);
    k_cvt<<<dim3(n * DDIM / 4 / 256), 256, 0, stream>>>(X, Xb);
    k_norm<<<dim3(n / 256), 256, 0, stream>>>(Xb, nrm);
    dim3 grid(n / 16, n / 8192);                 // (1024, 2)
    gauss_sweep<<<grid, 256, 0, stream>>>(Xb, nrm, K, n);
  } else {
    dim3 grid(n / 128, n / (128 * 8));
    gauss_gram_kernel<<<grid, 256, 0, stream>>>(X, K, n);
  }
}

// Round 12
// 224.988 us; speedup vs baseline: 1.4873x; 1.4873x over previous
//
#include <hip/hip_runtime.h>
#include <stdint.h>

// Gaussian kernel matrix K[i][j] = exp(-||x_i-x_j||^2/2), X: [16384][64] fp32.
// R12 = R6 verbatim (proven best: 223.9 us, 4.8 TB/s sustained writes).
// Structure: 128x128 tile/block, 4 drifting waves (2x2), A-resident strip
// mining (JT=8), swapped-operand MFMA, inline f32->bf16 cvt + norm fusion
// (exact diagonal cancellation), B prefetch issued BEFORE stores (vmcnt FIFO
// decoupling), VMEM-only sched_barrier, wave-private LDS transpose so each
// store instruction writes 8 rows x 128B full cache lines.
// Ladder: 339 (R1) -> 316 (A-resident+f32x4 stores) -> 252.7 (prefetch
// decouple) -> 223.9 (full-line stores). Flat: 256B spans, 3 waves/SIMD,
// depth-3 prefetch, prepass tables. Regressions: nontemporal, barriered
// cross-wave store shaping.

typedef __attribute__((ext_vector_type(8))) short s16x8;   // 8 bf16 (MFMA A/B frag)
typedef __attribute__((ext_vector_type(4))) float f32x4;

#define DDIM 64
#define JT 8
#define LROW 36   // LDS row stride in floats (32 data + 4 pad; 144B, 16B-aligned)
#define LOG2E      1.4426950408889634f   // 2c
#define HALF_LOG2E 0.7213475204444817f   // c ; K = exp2(-c||i||^2 - c||j||^2 + 2c dot)

// fp32 -> bf16 RNE on the bit pattern; accumulates rounded value^2 for norms.
__device__ inline short cvt1(float x, float& sq) {
  uint32_t u = __builtin_bit_cast(uint32_t, x);
  uint32_t r = (u + 0x7fffu + ((u >> 16) & 1u)) & 0xffff0000u;
  float hf = __builtin_bit_cast(float, r);
  sq += hf * hf;
  return (short)(r >> 16);
}

// Issue the 4 dwordx4 loads for one fragment row. Raw loads only.
__device__ inline void issue_row(const float* __restrict__ X, int row, int lq,
                                 f32x4 r[4]) {
  const f32x4* p = reinterpret_cast<const f32x4*>(X + (size_t)row * DDIM + lq * 8);
  const f32x4* q = reinterpret_cast<const f32x4*>(X + (size_t)row * DDIM + 32 + lq * 8);
  r[0] = p[0]; r[1] = p[1]; r[2] = q[0]; r[3] = q[1];
}

// Raw f32 row data -> bf16 MFMA fragments + premultiplied norm (-c*||x||^2).
__device__ inline void cvt_row(const f32x4 r[4], s16x8 h[2], float& hnorm) {
  float s = 0.f;
#pragma unroll
  for (int ks = 0; ks < 2; ++ks) {
    s16x8 hh;
    hh[0] = cvt1(r[2*ks][0], s);   hh[1] = cvt1(r[2*ks][1], s);
    hh[2] = cvt1(r[2*ks][2], s);   hh[3] = cvt1(r[2*ks][3], s);
    hh[4] = cvt1(r[2*ks+1][0], s); hh[5] = cvt1(r[2*ks+1][1], s);
    hh[6] = cvt1(r[2*ks+1][2], s); hh[7] = cvt1(r[2*ks+1][3], s);
    h[ks] = hh;
  }
  s += __shfl_xor(s, 16);
  s += __shfl_xor(s, 32);
  hnorm = -HALF_LOG2E * s;
}

__global__ __launch_bounds__(256, 2) void gauss_gram_kernel(
    const float* __restrict__ X, float* __restrict__ K, int n) {
  const int lane = threadIdx.x & 63;
  const int wid  = threadIdx.x >> 6;   // 4 waves: 2x2 over the 128x128 tile
  const int wr = wid >> 1;
  const int wc = wid & 1;
  const int l15 = lane & 15;
  const int lq  = lane >> 4;           // 0..3
  const int r8  = lane >> 3;           // 0..7  (transpose-read row within group)
  const int e8  = lane & 7;            // 0..7  (transpose-read col chunk)

  // Per-wave private transpose buffer: 64 rows x LROW floats (wave-synchronous).
  __shared__ float tbuf[4][64 * LROW];
  float* buf = tbuf[wid];

  const int i0     = blockIdx.x * 128 + wr * 64;   // output row base (this wave)
  const int jstrip = blockIdx.y * (128 * JT);      // column strip base

  // ---- prologue: issue A loads, then B(jt=0) loads; cvt A while B flies ----
  f32x4 araw[4][4];
#pragma unroll
  for (int mi = 0; mi < 4; ++mi)
    issue_row(X, i0 + mi * 16 + l15, lq, araw[mi]);

  f32x4 braw[4][4];
#pragma unroll
  for (int ni = 0; ni < 4; ++ni)
    issue_row(X, jstrip + wc * 64 + ni * 16 + l15, lq, braw[ni]);

  s16x8 a[4][2]; float hA[4];
#pragma unroll
  for (int mi = 0; mi < 4; ++mi)
    cvt_row(araw[mi], a[mi], hA[mi]);
  // hA[mi] at lane l is -c*||row (i0+mi*16+l15)||^2 == this lane's output row.

#pragma unroll
  for (int jt = 0; jt < JT; ++jt) {
    const int j0 = jstrip + jt * 128 + wc * 64;

    // ---- cvt current B (waits only on braw loads, older than any stores) ----
    s16x8 b[4][2]; float hcol[4][4];
#pragma unroll
    for (int ni = 0; ni < 4; ++ni) {
      float hB;
      cvt_row(braw[ni], b[ni], hB);
#pragma unroll
      for (int r = 0; r < 4; ++r)
        hcol[ni][r] = __shfl(hB, lq * 4 + r);   // -c*norm of col j0+ni*16+lq*4+r
    }

    // ---- prefetch next tile's B (issued ahead of this tile's stores) ----
    if (jt + 1 < JT) {
#pragma unroll
      for (int ni = 0; ni < 4; ++ni)
        issue_row(X, jstrip + (jt + 1) * 128 + wc * 64 + ni * 16 + l15, lq, braw[ni]);
    }
    // Pin VMEM order only: prefetch loads stay above the stores below.
    __builtin_amdgcn_sched_barrier(0x1 | 0x2 | 0x4 | 0x8);

    // ---- MFMA, swapped operands: lane's 4 acc regs = 4 consecutive cols ----
    f32x4 acc[4][4] = {};
#pragma unroll
    for (int ks = 0; ks < 2; ++ks)
#pragma unroll
      for (int mi = 0; mi < 4; ++mi)
#pragma unroll
        for (int ni = 0; ni < 4; ++ni)
          acc[mi][ni] = __builtin_amdgcn_mfma_f32_16x16x32_bf16(
              b[ni][ks], a[mi][ks], acc[mi][ni], 0, 0, 0);

    // ---- epilogue in two 32-col halves: exp -> LDS transpose -> full-line stores ----
#pragma unroll
    for (int half = 0; half < 2; ++half) {
      // exp + ds_write: lane (l15 row, lq*4 col chunk) -> buf[row][colchunk]
#pragma unroll
      for (int mi = 0; mi < 4; ++mi) {
        const int rg = i0 + mi * 16 + l15;
#pragma unroll
        for (int nh = 0; nh < 2; ++nh) {
          const int ni = half * 2 + nh;
          const int c0 = j0 + ni * 16 + lq * 4;
          f32x4 v;
#pragma unroll
          for (int r = 0; r < 4; ++r) {
            float arg = fminf(hA[mi] + hcol[ni][r] + LOG2E * acc[mi][ni][r], 0.0f);
            float e = exp2f(arg);
            v[r] = (rg == c0 + r) ? 1.0f : e;   // exact diagonal
          }
          *reinterpret_cast<f32x4*>(
              buf + (mi * 16 + l15) * LROW + nh * 16 + lq * 4) = v;
        }
      }
      // ds_read (8 rows x 32 consecutive floats per instr) -> full-line stores
#pragma unroll
      for (int g = 0; g < 8; ++g) {
        f32x4 t = *reinterpret_cast<const f32x4*>(
            buf + (g * 8 + r8) * LROW + e8 * 4);
        const int rg = i0 + g * 8 + r8;
        *reinterpret_cast<f32x4*>(
            K + (size_t)rg * n + j0 + half * 32 + e8 * 4) = t;
      }
    }
  }
}

extern "C" void kernel_launch(void* const* d_in, const int* in_sizes, int n_in,
                              void* d_out, int out_size, void* d_ws, size_t ws_size,
                              hipStream_t stream) {
  (void)n_in; (void)d_ws; (void)ws_size; (void)out_size;
  const float* X = (const float*)d_in[0];
  float* K = (float*)d_out;
  const int n = in_sizes[0] / DDIM;          // 16384
  dim3 grid(n / 128, n / (128 * JT));        // (128, 16)
  gauss_gram_kernel<<<grid, 256, 0, stream>>>(X, K, n);
}